// Round 8
// baseline (661.436 us; speedup 1.0000x reference)
//
#include <hip/hip_runtime.h>

// ---------------------------------------------------------------------------
// MultiModalRelationGraph — R21  (= R20 + agg DIAGNOSTIC + LN fused into agg)
// - R20 post-mortem: interleave = +7.8µs only (<20µs pre-commit threshold) ->
//   fetch-pattern theory insufficient. 3 rounds of unmeasured agg guesses
//   (R17/R19/R20) -> STOP: this round SURFACES agg counters.
// - DIAGNOSTIC: agg L0 runs PASSES=2 (same body twice per dispatch; reads
//   only h_bf -> idempotent; inter-pass barrier for LDS reuse). Dispatch dur
//   ~2x single-agg > gemm's 117µs -> top-5 visible with full counters.
//   Also: total - 598 ~= agg_single (independent estimate).
// - Kept improvement: LN fused into agg<true> MEAN branch (block holds the
//   full 256-dim row; wredx + 4-wave LDS stats); ln_pool -> pure pooling.
// - Decision rules (pre-committed): BW-bound -> traffic diet; VALUBusy-bound
//   -> wred chains; low-occ -> register diet; agg<45µs -> instrument proj.
// - Ledger: paired agg kills TLP (R19); occupancy forcing null (R18); 32x32
//   bank-conflicts (R17); BK=32 ring B-latency (R16); 256² lockstep null
//   (R15); strip-mining kills agg TLP (R8/R9); atomics flood (R10);
//   pure-global A+B L2-bound (R5); big AGPR kills occ (R3); proj×W0 re-cvt
//   (R12).
// Layout: region node (reg,b,t) -> row 4*(b*512+t)+reg; audio 32768+b*1024+ta.
// ---------------------------------------------------------------------------

typedef unsigned short u16;
typedef unsigned int u32;
typedef __bf16 bf16x8 __attribute__((ext_vector_type(8)));
typedef float f32x4 __attribute__((ext_vector_type(4)));

#define ASYNC16(gp, lp)                                                        \
  __builtin_amdgcn_global_load_lds(                                            \
      (const __attribute__((address_space(1))) void*)(gp),                     \
      (__attribute__((address_space(3))) void*)(lp), 16, 0, 0)

__device__ __forceinline__ u16 f2bf(float f) {
  union { float f; u32 u; } v; v.f = f;
  u32 u = v.u + 0x7FFFu + ((v.u >> 16) & 1u);  // RNE
  return (u16)(u >> 16);
}
__device__ __forceinline__ float bf2f(u16 x) {
  union { u32 u; float f; } v; v.u = ((u32)x) << 16;
  return v.f;
}
__device__ __forceinline__ float4 cvt4(ushort4 s) {
  float4 r; r.x = bf2f(s.x); r.y = bf2f(s.y); r.z = bf2f(s.z); r.w = bf2f(s.w);
  return r;
}
__device__ __forceinline__ float lrelu(float v) { return v > 0.f ? v : 0.2f * v; }
__device__ __forceinline__ float dot4(float4 a, float4 b) {
  return a.x * b.x + a.y * b.y + a.z * b.z + a.w * b.w;
}
__device__ __forceinline__ float wred(float v) {  // lane 0 valid
#pragma unroll
  for (int off = 32; off; off >>= 1) v += __shfl_down(v, off);
  return v;
}
__device__ __forceinline__ float wredx(float v) {  // all lanes valid
#pragma unroll
  for (int off = 32; off; off >>= 1) v += __shfl_xor(v, off);
  return v;
}

// ---------------- weight pack: W [K][N] fp32 -> MFMA B-fragment order -------
struct PK { const float* W[8]; u16* P[8]; int KB[8]; int NN[8]; int st[9]; };
__global__ __launch_bounds__(256) void pack_kernel(PK p) {
  const int f = blockIdx.x * 4 + (threadIdx.x >> 6);
  const int lane = threadIdx.x & 63;
  int e = 0;
  while (f >= p.st[e + 1]) ++e;
  const int local = f - p.st[e];
  const int KB = p.KB[e], N = p.NN[e];
  const int nt = local / KB, kb = local % KB;
  const float* W = p.W[e] + (size_t)(kb * 32 + (lane >> 4) * 8) * N + nt * 16 + (lane & 15);
  u16* dst = p.P[e] + ((size_t)local * 64 + lane) * 8;
  u16 o[8];
#pragma unroll
  for (int j = 0; j < 8; ++j) o[j] = f2bf(W[(size_t)j * N]);
  *(uint4*)dst = *(uint4*)o;
}

// ---------------- layer GEMM: C[M,N]=A[M,K]@W^T; BK=64 dbuf, B hoisted ------
// R13 verbatim (proven, 68 VGPR, 0 bank conflicts). Row-order agnostic.
__global__ __launch_bounds__(256) void gemm_kernel(
    const u16* __restrict__ A, const u16* __restrict__ Bp, u16* __restrict__ C,
    int K, int ldc) {
  __shared__ __align__(16) u16 As[2][2][128 * 32];
  const int KB = K >> 5;
  const int KB2 = K >> 6;
  const int w = blockIdx.y * 8 + blockIdx.x;
  const int xcd = w & 7, m = w >> 3;
  const int blockCol = (m & 7) * 128;
  const int blockRow = ((m >> 3) * 8 + xcd) * 128;
  const int tid = threadIdx.x;
  const int wave = tid >> 6, lane = tid & 63;
  const int wr = (wave >> 1) * 64, wc = (wave & 1) * 64;
  const int lr = lane & 15, lq = lane >> 4;
  const int sRow = wave * 16 + (lane >> 2);
  const int sGc = (lane & 3) ^ ((sRow >> 1) & 3);
  const size_t aOff0 = (size_t)(blockRow + sRow) * K + sGc * 8;
  const size_t aOff1 = aOff0 + (size_t)64 * K;
  const int ldsOff0 = wave * 512;
  const int ldsOff1 = 2048 + wave * 512;

  const u16* Bn[4];
#pragma unroll
  for (int ni = 0; ni < 4; ++ni)
    Bn[ni] = Bp + ((size_t)(((blockCol + wc) >> 4) + ni) * KB) * 512 + lane * 8;

  f32x4 acc[4][4] = {};

#pragma unroll
  for (int h = 0; h < 2; ++h) {
    ASYNC16(A + aOff0 + h * 32, As[0][h] + ldsOff0);
    ASYNC16(A + aOff1 + h * 32, As[0][h] + ldsOff1);
  }
  __syncthreads();

  for (int kb2 = 0; kb2 < KB2; ++kb2) {
    const int cb = kb2 & 1;
    bf16x8 bfr[2][4];
#pragma unroll
    for (int h = 0; h < 2; ++h)
#pragma unroll
      for (int ni = 0; ni < 4; ++ni)
        bfr[h][ni] = *(const bf16x8*)(Bn[ni] + (size_t)(kb2 * 2 + h) * 512);
    if (kb2 + 1 < KB2) {
      const size_t k1 = (size_t)(kb2 + 1) * 64;
#pragma unroll
      for (int h = 0; h < 2; ++h) {
        ASYNC16(A + aOff0 + k1 + h * 32, As[cb ^ 1][h] + ldsOff0);
        ASYNC16(A + aOff1 + k1 + h * 32, As[cb ^ 1][h] + ldsOff1);
      }
    }
#pragma unroll
    for (int h = 0; h < 2; ++h) {
      const u16* cur = As[cb][h];
      bf16x8 af[4];
#pragma unroll
      for (int mi = 0; mi < 4; ++mi) {
        const int R = wr + mi * 16 + lr;
        const int cp = lq ^ ((R >> 1) & 3);
        af[mi] = *(const bf16x8*)(cur + R * 32 + cp * 8);
      }
#pragma unroll
      for (int mi = 0; mi < 4; ++mi)
#pragma unroll
        for (int ni = 0; ni < 4; ++ni)
          acc[mi][ni] = __builtin_amdgcn_mfma_f32_16x16x32_bf16(af[mi], bfr[h][ni],
                                                                acc[mi][ni], 0, 0, 0);
    }
    __syncthreads();
  }
#pragma unroll
  for (int mi = 0; mi < 4; ++mi)
#pragma unroll
    for (int ni = 0; ni < 4; ++ni) {
      const int col = blockCol + wc + ni * 16 + lr;
#pragma unroll
      for (int r = 0; r < 4; ++r) {
        const int row = blockRow + wr + mi * 16 + lq * 4 + r;
        C[(size_t)row * ldc + col] = f2bf(acc[mi][ni][r]);
      }
    }
}

// ---------------- fused input projection (fp32 A in-register cvt) -----------
// Output rows remapped to interleaved layout: region row -> 4*bt + reg.
struct ProjArgs { const float* x[5]; const u16* w[5]; const float* b[5]; };
__global__ __launch_bounds__(256) void proj_kernel(ProjArgs pa,
                                                   u16* __restrict__ C) {
  __shared__ __align__(16) u16 As[128 * 32];
  const int blockRow = blockIdx.y * 128, blockCol = blockIdx.x * 128;
  const int reg = blockRow >= 32768 ? 4 : (blockRow >> 13);
  const int regBase = reg == 4 ? 32768 : reg * 8192;
  const float* Af = pa.x[reg] + (size_t)(blockRow - regBase) * 512;
  const u16* Bp = pa.w[reg];
  const int tid = threadIdx.x;
  const int wave = tid >> 6, lane = tid & 63;
  const int wr = (wave >> 1) * 64, wc = (wave & 1) * 64;
  const int lr = lane & 15, lq = lane >> 4;
  const int rr = tid >> 2;
  const int cphys = tid & 3;
  const int sGc = cphys ^ ((tid >> 3) & 3);

  const u16* Bn[4];
#pragma unroll
  for (int ni = 0; ni < 4; ++ni)
    Bn[ni] = Bp + ((size_t)(((blockCol + wc) >> 4) + ni) * 16) * 512 + lane * 8;

  f32x4 acc[4][4] = {};

  for (int k0 = 0; k0 < 512; k0 += 32) {
    __syncthreads();
    bf16x8 bfr[4];
#pragma unroll
    for (int ni = 0; ni < 4; ++ni)
      bfr[ni] = *(const bf16x8*)(Bn[ni] + (size_t)k0 * 16);
#pragma unroll
    for (int i = 0; i < 2; ++i) {
      const int row = i * 64 + rr;
      const float* ap = Af + (size_t)row * 512 + k0 + sGc * 8;
      float4 f0 = *(const float4*)(ap);
      float4 f1 = *(const float4*)(ap + 4);
      uint4 pk;
      pk.x = (u32)f2bf(f0.x) | ((u32)f2bf(f0.y) << 16);
      pk.y = (u32)f2bf(f0.z) | ((u32)f2bf(f0.w) << 16);
      pk.z = (u32)f2bf(f1.x) | ((u32)f2bf(f1.y) << 16);
      pk.w = (u32)f2bf(f1.z) | ((u32)f2bf(f1.w) << 16);
      *(uint4*)(&As[row * 32 + cphys * 8]) = pk;
    }
    __syncthreads();
    bf16x8 af[4];
#pragma unroll
    for (int mi = 0; mi < 4; ++mi) {
      const int R = wr + mi * 16 + lr;
      const int cp = lq ^ ((R >> 1) & 3);
      af[mi] = *(const bf16x8*)(&As[R * 32 + cp * 8]);
    }
#pragma unroll
    for (int mi = 0; mi < 4; ++mi)
#pragma unroll
      for (int ni = 0; ni < 4; ++ni)
        acc[mi][ni] = __builtin_amdgcn_mfma_f32_16x16x32_bf16(af[mi], bfr[ni],
                                                              acc[mi][ni], 0, 0, 0);
  }
  const float* bias = pa.b[reg];
#pragma unroll
  for (int mi = 0; mi < 4; ++mi)
#pragma unroll
    for (int ni = 0; ni < 4; ++ni) {
      const int col = blockCol + wc + ni * 16 + lr;
      const float bv = bias[col];
#pragma unroll
      for (int r = 0; r < 4; ++r) {
        const int row = blockRow + wr + mi * 16 + lq * 4 + r;
        const int nrow = (reg == 4) ? row : ((row - regBase) * 4 + reg);
        C[(size_t)nrow * 256 + col] = f2bf(acc[mi][ni][r] + bv);
      }
    }
}

// ---------------- merged aggregation: block (b,t) -> 6 dst nodes ------------
// Interleaved layout. PASSES>1 = diagnostic (idempotent: reads only h).
// MEAN branch fuses LayerNorm (full row resident in block).
template <bool MEAN, int PASSES>
__global__ __launch_bounds__(256) void agg_kernel(
    const u16* __restrict__ h, const float* __restrict__ a_s,
    const float* __restrict__ a_d, const float* __restrict__ bias,
    const float* __restrict__ ln_g, const float* __restrict__ ln_b,
    void* __restrict__ out) {
  extern __shared__ float red[];  // MEAN only: [6][1024]
  const int tid = threadIdx.x;
  const int head = tid >> 6, lane = tid & 63;
  const int c4 = tid * 4;
  const float4 sa = *(const float4*)(a_s + c4);
  const float4 da = *(const float4*)(a_d + c4);
  __shared__ float asL[4][4], adL[4][4], apL[4][4], aeS[4], aeD[4];
  __shared__ float alpha[4][4][5], alphaA[4][3];
  __shared__ float stats[6][2][4];  // MEAN only: row sums / sumsq per wave

  const int bid = blockIdx.x;
  const int bt = ((bid & 7) << 10) | (bid >> 3);  // bijective XCD chunking
  const int b = bt >> 9, t = bt & 511;
  const bool hasPrev = t > 0;
  const int btp = hasPrev ? bt - 1 : bt;  // clamped: loads valid, result unused at t==0
  const int rb = bt * 4, rbp = btp * 4;   // interleaved region row bases
  const int nodeE = 32768 + b * 1024 + 2 * t;
  const int nodeO = nodeE + 1;

  for (int pass = 0; pass < PASSES; ++pass) {
    // ---- batched raw loads (no cvt until all issued) ----
    ushort4 rv[4], rp[4], raeR, raoR;
#pragma unroll
    for (int r = 0; r < 4; ++r)
      rv[r] = *(const ushort4*)(h + (size_t)(rb + r) * 1024 + c4);
    raeR = *(const ushort4*)(h + (size_t)nodeE * 1024 + c4);
    raoR = *(const ushort4*)(h + (size_t)nodeO * 1024 + c4);
#pragma unroll
    for (int r = 0; r < 4; ++r)
      rp[r] = *(const ushort4*)(h + (size_t)(rbp + r) * 1024 + c4);

    float4 hv[4], hp[4];
#pragma unroll
    for (int r = 0; r < 4; ++r) hv[r] = cvt4(rv[r]);
    float4 hae = cvt4(raeR), hao = cvt4(raoR);
#pragma unroll
    for (int r = 0; r < 4; ++r) hp[r] = cvt4(rp[r]);

    // dots (wave w == head w); lane0-valid wred, stash to LDS
#pragma unroll
    for (int r = 0; r < 4; ++r) {
      float ss = wred(dot4(hv[r], sa));
      float dd = wred(dot4(hv[r], da));
      float sp = hasPrev ? wred(dot4(hp[r], sa)) : 0.f;
      if (lane == 0) { asL[r][head] = ss; adL[r][head] = dd; apL[r][head] = sp; }
    }
    {
      float se = wred(dot4(hae, sa));
      float de = wred(dot4(hae, da));
      if (lane == 0) { aeS[head] = se; aeD[head] = de; }
    }
    __syncthreads();
    if (tid < 16) {
      const int j = tid >> 2, hh = tid & 3;
      const float ad = adL[j][hh];
      float e[5];
#pragma unroll
      for (int r = 0; r < 4; ++r) e[r] = lrelu(asL[r][hh] + ad);
      int cnt = 4;
      if (hasPrev) { e[4] = lrelu(apL[j][hh] + ad); cnt = 5; }
      float mx = e[0];
      for (int k = 1; k < cnt; ++k) mx = fmaxf(mx, e[k]);
      float s = 0.f, ex[5];
      for (int k = 0; k < cnt; ++k) { ex[k] = __expf(e[k] - mx); s += ex[k]; }
      const float inv = 1.f / (s + 1e-16f);
#pragma unroll
      for (int k = 0; k < 5; ++k) alpha[j][hh][k] = (k < cnt) ? ex[k] * inv : 0.f;
    } else if (tid < 20) {
      const int hh = tid - 16;  // audio-even softmax: {self, left eye, right eye}
      const float ad = aeD[hh];
      const float e0 = lrelu(aeS[hh] + ad);
      const float e1 = lrelu(asL[1][hh] + ad);
      const float e2 = lrelu(asL[2][hh] + ad);
      const float mx = fmaxf(e0, fmaxf(e1, e2));
      const float x0 = __expf(e0 - mx), x1 = __expf(e1 - mx), x2 = __expf(e2 - mx);
      const float inv = 1.f / (x0 + x1 + x2 + 1e-16f);
      alphaA[hh][0] = x0 * inv; alphaA[hh][1] = x1 * inv; alphaA[hh][2] = x2 * inv;
    }
    __syncthreads();

    float4 av[6];
#pragma unroll
    for (int j = 0; j < 4; ++j) {
      const float* al = &alpha[j][head][0];
      float4 acc;
      acc.x = al[0] * hv[0].x + al[1] * hv[1].x + al[2] * hv[2].x + al[3] * hv[3].x;
      acc.y = al[0] * hv[0].y + al[1] * hv[1].y + al[2] * hv[2].y + al[3] * hv[3].y;
      acc.z = al[0] * hv[0].z + al[1] * hv[1].z + al[2] * hv[2].z + al[3] * hv[3].z;
      acc.w = al[0] * hv[0].w + al[1] * hv[1].w + al[2] * hv[2].w + al[3] * hv[3].w;
      if (hasPrev) {
        const float a4 = al[4];
        acc.x += a4 * hp[j].x; acc.y += a4 * hp[j].y;
        acc.z += a4 * hp[j].z; acc.w += a4 * hp[j].w;
      }
      av[j] = acc;
    }
    {
      const float a0 = alphaA[head][0], a1 = alphaA[head][1], a2 = alphaA[head][2];
      float4 acc;
      acc.x = a0 * hae.x + a1 * hv[1].x + a2 * hv[2].x;
      acc.y = a0 * hae.y + a1 * hv[1].y + a2 * hv[2].y;
      acc.z = a0 * hae.z + a1 * hv[1].z + a2 * hv[2].z;
      acc.w = a0 * hae.w + a1 * hv[1].w + a2 * hv[2].w;
      av[4] = acc;
      av[5] = hao;  // odd audio: self-loop only
    }

    size_t rows[6];
#pragma unroll
    for (int j = 0; j < 4; ++j) rows[j] = (size_t)(rb + j);
    rows[4] = (size_t)nodeE; rows[5] = (size_t)nodeO;

    if constexpr (!MEAN) {
      const float4 bv = *(const float4*)(bias + c4);
      u16* ob = (u16*)out;
#pragma unroll
      for (int k = 0; k < 6; ++k) {
        ushort4 o;
        o.x = f2bf(av[k].x + bv.x); o.y = f2bf(av[k].y + bv.y);
        o.z = f2bf(av[k].z + bv.z); o.w = f2bf(av[k].w + bv.w);
        *(ushort4*)(ob + rows[k] * 1024 + c4) = o;
      }
    } else {
      // head-mean + bias, then FUSED LayerNorm (full row resident in block)
#pragma unroll
      for (int k = 0; k < 6; ++k) *(float4*)(&red[k * 1024 + c4]) = av[k];
      __syncthreads();
      const float bb2 = bias[tid];
      float vv[6];
#pragma unroll
      for (int k = 0; k < 6; ++k) {
        const float v = 0.25f * (red[k * 1024 + tid] + red[k * 1024 + tid + 256] +
                                 red[k * 1024 + tid + 512] + red[k * 1024 + tid + 768]) + bb2;
        vv[k] = v;
        const float ws = wredx(v);
        const float wq = wredx(v * v);
        if (lane == 0) { stats[k][0][head] = ws; stats[k][1][head] = wq; }
      }
      __syncthreads();
      const float gg = ln_g[tid], lb = ln_b[tid];
      float* of = (float*)out;
#pragma unroll
      for (int k = 0; k < 6; ++k) {
        const float sum = stats[k][0][0] + stats[k][0][1] + stats[k][0][2] + stats[k][0][3];
        const float sq = stats[k][1][0] + stats[k][1][1] + stats[k][1][2] + stats[k][1][3];
        const float mean = sum * (1.f / 256.f);
        const float var = sq * (1.f / 256.f) - mean * mean;
        const float rstd = rsqrtf(var + 1e-5f);
        of[rows[k] * 256 + tid] = (vv[k] - mean) * rstd * gg + lb;
      }
    }
    if (pass + 1 < PASSES) __syncthreads();  // LDS reuse across passes
  }
}

// ---------------- pure pooling stage 1 (OLD-row keyed; LN already applied) --
// Reference pools OLD-order 3072-row chunks; block p handles OLD rows
// [64p, 64p+64); region rows gather stride-4 from interleaved xf.
__global__ __launch_bounds__(256) void ln_pool_kernel(
    const float* __restrict__ xf, float* __restrict__ part) {
  __shared__ float sh[1024];
  const int tid = threadIdx.x;
  const int wave = tid >> 6, lane = tid & 63;
  const int node0 = blockIdx.x * 64 + wave * 16;  // OLD row base (one region)
  const bool isAud = node0 >= 32768;
  const int reg = isAud ? 4 : (node0 >> 13);
  const int bt0 = node0 & 8191;
  float4 acc = {0.f, 0.f, 0.f, 0.f};
  for (int i = 0; i < 16; ++i) {
    const size_t nrow = isAud ? (size_t)(node0 + i) : (size_t)((bt0 + i) * 4 + reg);
    const float4 v = *(const float4*)(xf + nrow * 256 + lane * 4);
    acc.x += v.x; acc.y += v.y; acc.z += v.z; acc.w += v.w;
  }
  *(float4*)(&sh[wave * 256 + lane * 4]) = acc;
  __syncthreads();
  const float s = sh[tid] + sh[256 + tid] + sh[512 + tid] + sh[768 + tid];
  part[(size_t)blockIdx.x * 256 + tid] = s;
}

__global__ __launch_bounds__(256) void pool2_kernel(const float* __restrict__ part,
                                                    float* __restrict__ out) {
  const int chunk = blockIdx.x;
  const int c = threadIdx.x;
  float s = 0.f;
  for (int i = 0; i < 48; ++i) s += part[(size_t)(chunk * 48 + i) * 256 + c];
  out[chunk * 256 + c] = s * (1.f / 3072.f);
}

// ---------------------------------------------------------------------------
extern "C" void kernel_launch(void* const* d_in, const int* in_sizes, int n_in,
                              void* d_out, int out_size, void* d_ws, size_t ws_size,
                              hipStream_t stream) {
  const float* x_reg[4] = {(const float*)d_in[0], (const float*)d_in[1],
                           (const float*)d_in[2], (const float*)d_in[3]};
  const float* audio = (const float*)d_in[4];
  const float* w_reg[4] = {(const float*)d_in[5], (const float*)d_in[7],
                           (const float*)d_in[9], (const float*)d_in[11]};
  const float* b_reg[4] = {(const float*)d_in[6], (const float*)d_in[8],
                           (const float*)d_in[10], (const float*)d_in[12]};
  const float* w_aud = (const float*)d_in[13];
  const float* b_aud = (const float*)d_in[14];
  const float* Wl[3] = {(const float*)d_in[15], (const float*)d_in[19],
                        (const float*)d_in[23]};
  const float* as_in[3] = {(const float*)d_in[16], (const float*)d_in[20],
                           (const float*)d_in[24]};
  const float* ad_in[3] = {(const float*)d_in[17], (const float*)d_in[21],
                           (const float*)d_in[25]};
  const float* bias_l[3] = {(const float*)d_in[18], (const float*)d_in[22],
                            (const float*)d_in[26]};
  const float* ln_g = (const float*)d_in[27];
  const float* ln_b = (const float*)d_in[28];

  // workspace layout (<200 MiB)
  char* ws = (char*)d_ws;
  u16* h_bf = (u16*)ws;                    // [N,1024] bf16 (96 MiB)
  float* part = (float*)ws;                // ln partials (h dead by then)
  u16* xb = (u16*)(ws + 100663296);        // [N,1024] bf16 x buffer
  float* xf = (float*)xb;                  // layer-2 output [N,256] fp32
  u16* wt = (u16*)(ws + 201326592);        // packed bf16 weights (~5.8 MiB)

  u16* wtp[5];
  for (int r = 0; r < 5; ++r) wtp[r] = wt + (size_t)r * 131072;
  u16* wt0 = wt + 655360;   // 512 frags
  u16* wt1 = wt + 917504;   // 2048 frags
  u16* wt2 = wt + 1966080;  // 2048 frags

  // 1) pack all weights into MFMA fragment order
  PK pk;
  for (int r = 0; r < 4; ++r) { pk.W[r] = w_reg[r]; pk.P[r] = wtp[r]; pk.KB[r] = 16; pk.NN[r] = 256; }
  pk.W[4] = w_aud; pk.P[4] = wtp[4]; pk.KB[4] = 16; pk.NN[4] = 256;
  pk.W[5] = Wl[0]; pk.P[5] = wt0; pk.KB[5] = 8;  pk.NN[5] = 1024;
  pk.W[6] = Wl[1]; pk.P[6] = wt1; pk.KB[6] = 32; pk.NN[6] = 1024;
  pk.W[7] = Wl[2]; pk.P[7] = wt2; pk.KB[7] = 32; pk.NN[7] = 1024;
  pk.st[0] = 0;
  {
    const int nfr[8] = {256, 256, 256, 256, 256, 512, 2048, 2048};
    int acc = 0;
    for (int e = 0; e < 8; ++e) { acc += nfr[e]; pk.st[e + 1] = acc; }
  }
  pack_kernel<<<pk.st[8] / 4, 256, 0, stream>>>(pk);

  // 2) fused input projections (fp32 in, bf16 out) -> x0 [N,256] interleaved
  ProjArgs pa;
  for (int r = 0; r < 4; ++r) { pa.x[r] = x_reg[r]; pa.w[r] = wtp[r]; pa.b[r] = b_reg[r]; }
  pa.x[4] = audio; pa.w[4] = wtp[4]; pa.b[4] = b_aud;
  proj_kernel<<<dim3(2, 384), 256, 0, stream>>>(pa, xb);

  // 3) three GAT layers. L0 agg = PASSES=2 DIAGNOSTIC (idempotent).
  const size_t dynLds = 6 * 1024 * sizeof(float);
  gemm_kernel<<<dim3(8, 384), 256, 0, stream>>>(xb, wt0, h_bf, 256, 1024);
  agg_kernel<false, 2><<<8192, 256, 0, stream>>>(h_bf, as_in[0], ad_in[0],
                                                 bias_l[0], ln_g, ln_b, xb);
  gemm_kernel<<<dim3(8, 384), 256, 0, stream>>>(xb, wt1, h_bf, 1024, 1024);
  agg_kernel<false, 1><<<8192, 256, 0, stream>>>(h_bf, as_in[1], ad_in[1],
                                                 bias_l[1], ln_g, ln_b, xb);
  gemm_kernel<<<dim3(8, 384), 256, 0, stream>>>(xb, wt2, h_bf, 1024, 1024);
  agg_kernel<true, 1><<<8192, 256, dynLds, stream>>>(h_bf, as_in[2], ad_in[2],
                                                     bias_l[2], ln_g, ln_b, xf);

  // 4) pooling -> out [16,256]  (LN already applied in agg L2)
  ln_pool_kernel<<<768, 256, 0, stream>>>(xf, part);
  pool2_kernel<<<16, 256, 0, stream>>>(part, (float*)d_out);
}

// Round 9
// 603.699 us; speedup vs baseline: 1.0956x; 1.0956x over previous
//
#include <hip/hip_runtime.h>

// ---------------------------------------------------------------------------
// MultiModalRelationGraph — R22  (= R21 minus diagnostic, plus wred4 diet)
// - R21 diagnostic result: doubled-agg NOT in top-5 (<117µs) + total delta
//   +63µs -> single agg ~= 55µs vs ~32µs traffic floor. Overhead audit: 14
//   wave-reduces x 6 shuffle stages = 84 LDS-pipe ops/thread dominates the
//   non-BW cost. Odd-audio gemm-epilogue bypass is RACY (xb read stride 256
//   vs write stride 1024 in-place) — ledgered, not attempted.
// - R22: wred4 (4-stage, lanes 0-3 partials -> LDS[4]; softmax threads finish
//   with 3 adds/value): -28 shuffles -28 adds per thread (-33% shuffle
//   budget). PASSES diag removed. LN-fused MEAN agg kept (R21). Interleaved
//   layout + XCD chunk kept (R20). R13 gemm untouched.
// - Pre-commit: total >= 593 -> agg latency/BW-bound -> roofline assessment
//   next round (gemm 92% of structure ceiling, agg near BW floor, proj
//   mem-bound).
// - Ledger: odd-audio bypass racy (R21); paired agg kills TLP (R19);
//   occupancy forcing null (R18); 32x32 bank-conflicts (R17); BK=32 ring
//   B-latency (R16); 256² lockstep null (R15); strip-mining kills agg TLP
//   (R8/R9); atomics flood (R10); pure-global A+B L2-bound (R5); big AGPR
//   kills occ (R3); proj×W0 re-cvt (R12).
// Layout: region node (reg,b,t) -> row 4*(b*512+t)+reg; audio 32768+b*1024+ta.
// ---------------------------------------------------------------------------

typedef unsigned short u16;
typedef unsigned int u32;
typedef __bf16 bf16x8 __attribute__((ext_vector_type(8)));
typedef float f32x4 __attribute__((ext_vector_type(4)));

#define ASYNC16(gp, lp)                                                        \
  __builtin_amdgcn_global_load_lds(                                            \
      (const __attribute__((address_space(1))) void*)(gp),                     \
      (__attribute__((address_space(3))) void*)(lp), 16, 0, 0)

__device__ __forceinline__ u16 f2bf(float f) {
  union { float f; u32 u; } v; v.f = f;
  u32 u = v.u + 0x7FFFu + ((v.u >> 16) & 1u);  // RNE
  return (u16)(u >> 16);
}
__device__ __forceinline__ float bf2f(u16 x) {
  union { u32 u; float f; } v; v.u = ((u32)x) << 16;
  return v.f;
}
__device__ __forceinline__ float4 cvt4(ushort4 s) {
  float4 r; r.x = bf2f(s.x); r.y = bf2f(s.y); r.z = bf2f(s.z); r.w = bf2f(s.w);
  return r;
}
__device__ __forceinline__ float lrelu(float v) { return v > 0.f ? v : 0.2f * v; }
__device__ __forceinline__ float dot4(float4 a, float4 b) {
  return a.x * b.x + a.y * b.y + a.z * b.z + a.w * b.w;
}
__device__ __forceinline__ float wred4(float v) {  // lanes 0-3 hold partials
  v += __shfl_down(v, 32);
  v += __shfl_down(v, 16);
  v += __shfl_down(v, 8);
  v += __shfl_down(v, 4);
  return v;  // lane l<4: sum over lanes ≡ l (mod 4)
}
__device__ __forceinline__ float wredx(float v) {  // all lanes valid
#pragma unroll
  for (int off = 32; off; off >>= 1) v += __shfl_xor(v, off);
  return v;
}

// ---------------- weight pack: W [K][N] fp32 -> MFMA B-fragment order -------
struct PK { const float* W[8]; u16* P[8]; int KB[8]; int NN[8]; int st[9]; };
__global__ __launch_bounds__(256) void pack_kernel(PK p) {
  const int f = blockIdx.x * 4 + (threadIdx.x >> 6);
  const int lane = threadIdx.x & 63;
  int e = 0;
  while (f >= p.st[e + 1]) ++e;
  const int local = f - p.st[e];
  const int KB = p.KB[e], N = p.NN[e];
  const int nt = local / KB, kb = local % KB;
  const float* W = p.W[e] + (size_t)(kb * 32 + (lane >> 4) * 8) * N + nt * 16 + (lane & 15);
  u16* dst = p.P[e] + ((size_t)local * 64 + lane) * 8;
  u16 o[8];
#pragma unroll
  for (int j = 0; j < 8; ++j) o[j] = f2bf(W[(size_t)j * N]);
  *(uint4*)dst = *(uint4*)o;
}

// ---------------- layer GEMM: C[M,N]=A[M,K]@W^T; BK=64 dbuf, B hoisted ------
// R13 verbatim (proven, 68 VGPR, 0 bank conflicts). Row-order agnostic.
__global__ __launch_bounds__(256) void gemm_kernel(
    const u16* __restrict__ A, const u16* __restrict__ Bp, u16* __restrict__ C,
    int K, int ldc) {
  __shared__ __align__(16) u16 As[2][2][128 * 32];
  const int KB = K >> 5;
  const int KB2 = K >> 6;
  const int w = blockIdx.y * 8 + blockIdx.x;
  const int xcd = w & 7, m = w >> 3;
  const int blockCol = (m & 7) * 128;
  const int blockRow = ((m >> 3) * 8 + xcd) * 128;
  const int tid = threadIdx.x;
  const int wave = tid >> 6, lane = tid & 63;
  const int wr = (wave >> 1) * 64, wc = (wave & 1) * 64;
  const int lr = lane & 15, lq = lane >> 4;
  const int sRow = wave * 16 + (lane >> 2);
  const int sGc = (lane & 3) ^ ((sRow >> 1) & 3);
  const size_t aOff0 = (size_t)(blockRow + sRow) * K + sGc * 8;
  const size_t aOff1 = aOff0 + (size_t)64 * K;
  const int ldsOff0 = wave * 512;
  const int ldsOff1 = 2048 + wave * 512;

  const u16* Bn[4];
#pragma unroll
  for (int ni = 0; ni < 4; ++ni)
    Bn[ni] = Bp + ((size_t)(((blockCol + wc) >> 4) + ni) * KB) * 512 + lane * 8;

  f32x4 acc[4][4] = {};

#pragma unroll
  for (int h = 0; h < 2; ++h) {
    ASYNC16(A + aOff0 + h * 32, As[0][h] + ldsOff0);
    ASYNC16(A + aOff1 + h * 32, As[0][h] + ldsOff1);
  }
  __syncthreads();

  for (int kb2 = 0; kb2 < KB2; ++kb2) {
    const int cb = kb2 & 1;
    bf16x8 bfr[2][4];
#pragma unroll
    for (int h = 0; h < 2; ++h)
#pragma unroll
      for (int ni = 0; ni < 4; ++ni)
        bfr[h][ni] = *(const bf16x8*)(Bn[ni] + (size_t)(kb2 * 2 + h) * 512);
    if (kb2 + 1 < KB2) {
      const size_t k1 = (size_t)(kb2 + 1) * 64;
#pragma unroll
      for (int h = 0; h < 2; ++h) {
        ASYNC16(A + aOff0 + k1 + h * 32, As[cb ^ 1][h] + ldsOff0);
        ASYNC16(A + aOff1 + k1 + h * 32, As[cb ^ 1][h] + ldsOff1);
      }
    }
#pragma unroll
    for (int h = 0; h < 2; ++h) {
      const u16* cur = As[cb][h];
      bf16x8 af[4];
#pragma unroll
      for (int mi = 0; mi < 4; ++mi) {
        const int R = wr + mi * 16 + lr;
        const int cp = lq ^ ((R >> 1) & 3);
        af[mi] = *(const bf16x8*)(cur + R * 32 + cp * 8);
      }
#pragma unroll
      for (int mi = 0; mi < 4; ++mi)
#pragma unroll
        for (int ni = 0; ni < 4; ++ni)
          acc[mi][ni] = __builtin_amdgcn_mfma_f32_16x16x32_bf16(af[mi], bfr[h][ni],
                                                                acc[mi][ni], 0, 0, 0);
    }
    __syncthreads();
  }
#pragma unroll
  for (int mi = 0; mi < 4; ++mi)
#pragma unroll
    for (int ni = 0; ni < 4; ++ni) {
      const int col = blockCol + wc + ni * 16 + lr;
#pragma unroll
      for (int r = 0; r < 4; ++r) {
        const int row = blockRow + wr + mi * 16 + lq * 4 + r;
        C[(size_t)row * ldc + col] = f2bf(acc[mi][ni][r]);
      }
    }
}

// ---------------- fused input projection (fp32 A in-register cvt) -----------
// Output rows remapped to interleaved layout: region row -> 4*bt + reg.
struct ProjArgs { const float* x[5]; const u16* w[5]; const float* b[5]; };
__global__ __launch_bounds__(256) void proj_kernel(ProjArgs pa,
                                                   u16* __restrict__ C) {
  __shared__ __align__(16) u16 As[128 * 32];
  const int blockRow = blockIdx.y * 128, blockCol = blockIdx.x * 128;
  const int reg = blockRow >= 32768 ? 4 : (blockRow >> 13);
  const int regBase = reg == 4 ? 32768 : reg * 8192;
  const float* Af = pa.x[reg] + (size_t)(blockRow - regBase) * 512;
  const u16* Bp = pa.w[reg];
  const int tid = threadIdx.x;
  const int wave = tid >> 6, lane = tid & 63;
  const int wr = (wave >> 1) * 64, wc = (wave & 1) * 64;
  const int lr = lane & 15, lq = lane >> 4;
  const int rr = tid >> 2;
  const int cphys = tid & 3;
  const int sGc = cphys ^ ((tid >> 3) & 3);

  const u16* Bn[4];
#pragma unroll
  for (int ni = 0; ni < 4; ++ni)
    Bn[ni] = Bp + ((size_t)(((blockCol + wc) >> 4) + ni) * 16) * 512 + lane * 8;

  f32x4 acc[4][4] = {};

  for (int k0 = 0; k0 < 512; k0 += 32) {
    __syncthreads();
    bf16x8 bfr[4];
#pragma unroll
    for (int ni = 0; ni < 4; ++ni)
      bfr[ni] = *(const bf16x8*)(Bn[ni] + (size_t)k0 * 16);
#pragma unroll
    for (int i = 0; i < 2; ++i) {
      const int row = i * 64 + rr;
      const float* ap = Af + (size_t)row * 512 + k0 + sGc * 8;
      float4 f0 = *(const float4*)(ap);
      float4 f1 = *(const float4*)(ap + 4);
      uint4 pk;
      pk.x = (u32)f2bf(f0.x) | ((u32)f2bf(f0.y) << 16);
      pk.y = (u32)f2bf(f0.z) | ((u32)f2bf(f0.w) << 16);
      pk.z = (u32)f2bf(f1.x) | ((u32)f2bf(f1.y) << 16);
      pk.w = (u32)f2bf(f1.z) | ((u32)f2bf(f1.w) << 16);
      *(uint4*)(&As[row * 32 + cphys * 8]) = pk;
    }
    __syncthreads();
    bf16x8 af[4];
#pragma unroll
    for (int mi = 0; mi < 4; ++mi) {
      const int R = wr + mi * 16 + lr;
      const int cp = lq ^ ((R >> 1) & 3);
      af[mi] = *(const bf16x8*)(&As[R * 32 + cp * 8]);
    }
#pragma unroll
    for (int mi = 0; mi < 4; ++mi)
#pragma unroll
      for (int ni = 0; ni < 4; ++ni)
        acc[mi][ni] = __builtin_amdgcn_mfma_f32_16x16x32_bf16(af[mi], bfr[ni],
                                                              acc[mi][ni], 0, 0, 0);
  }
  const float* bias = pa.b[reg];
#pragma unroll
  for (int mi = 0; mi < 4; ++mi)
#pragma unroll
    for (int ni = 0; ni < 4; ++ni) {
      const int col = blockCol + wc + ni * 16 + lr;
      const float bv = bias[col];
#pragma unroll
      for (int r = 0; r < 4; ++r) {
        const int row = blockRow + wr + mi * 16 + lq * 4 + r;
        const int nrow = (reg == 4) ? row : ((row - regBase) * 4 + reg);
        C[(size_t)nrow * 256 + col] = f2bf(acc[mi][ni][r] + bv);
      }
    }
}

// ---------------- merged aggregation: block (b,t) -> 6 dst nodes ------------
// Interleaved layout; wred4 partial reduction (lanes 0-3 -> LDS[4], softmax
// threads finish). MEAN branch fuses LayerNorm.
template <bool MEAN>
__global__ __launch_bounds__(256) void agg_kernel(
    const u16* __restrict__ h, const float* __restrict__ a_s,
    const float* __restrict__ a_d, const float* __restrict__ bias,
    const float* __restrict__ ln_g, const float* __restrict__ ln_b,
    void* __restrict__ out) {
  extern __shared__ float red[];  // MEAN only: [6][1024]
  const int tid = threadIdx.x;
  const int head = tid >> 6, lane = tid & 63;
  const int c4 = tid * 4;
  const float4 sa = *(const float4*)(a_s + c4);
  const float4 da = *(const float4*)(a_d + c4);
  __shared__ float asL[4][4][4], adL[4][4][4], apL[4][4][4], aeS[4][4], aeD[4][4];
  __shared__ float alpha[4][4][5], alphaA[4][3];
  __shared__ float stats[6][2][4];  // MEAN only: row sums / sumsq per wave

  const int bid = blockIdx.x;
  const int bt = ((bid & 7) << 10) | (bid >> 3);  // bijective XCD chunking
  const int b = bt >> 9, t = bt & 511;
  const bool hasPrev = t > 0;
  const int btp = hasPrev ? bt - 1 : bt;  // clamped: loads valid, result unused at t==0
  const int rb = bt * 4, rbp = btp * 4;   // interleaved region row bases
  const int nodeE = 32768 + b * 1024 + 2 * t;
  const int nodeO = nodeE + 1;

  // ---- batched raw loads (no cvt until all issued) ----
  ushort4 rv[4], rp[4], raeR, raoR;
#pragma unroll
  for (int r = 0; r < 4; ++r)
    rv[r] = *(const ushort4*)(h + (size_t)(rb + r) * 1024 + c4);
  raeR = *(const ushort4*)(h + (size_t)nodeE * 1024 + c4);
  raoR = *(const ushort4*)(h + (size_t)nodeO * 1024 + c4);
#pragma unroll
  for (int r = 0; r < 4; ++r)
    rp[r] = *(const ushort4*)(h + (size_t)(rbp + r) * 1024 + c4);

  float4 hv[4], hp[4];
#pragma unroll
  for (int r = 0; r < 4; ++r) hv[r] = cvt4(rv[r]);
  float4 hae = cvt4(raeR), hao = cvt4(raoR);
#pragma unroll
  for (int r = 0; r < 4; ++r) hp[r] = cvt4(rp[r]);

  // dots (wave w == head w); wred4 -> lanes 0-3 stash partials to LDS
#pragma unroll
  for (int r = 0; r < 4; ++r) {
    float ss = wred4(dot4(hv[r], sa));
    float dd = wred4(dot4(hv[r], da));
    float sp = hasPrev ? wred4(dot4(hp[r], sa)) : 0.f;
    if (lane < 4) { asL[r][head][lane] = ss; adL[r][head][lane] = dd; apL[r][head][lane] = sp; }
  }
  {
    float se = wred4(dot4(hae, sa));
    float de = wred4(dot4(hae, da));
    if (lane < 4) { aeS[head][lane] = se; aeD[head][lane] = de; }
  }
  __syncthreads();
  if (tid < 16) {
    const int j = tid >> 2, hh = tid & 3;
    const float ad = adL[j][hh][0] + adL[j][hh][1] + adL[j][hh][2] + adL[j][hh][3];
    float e[5];
#pragma unroll
    for (int r = 0; r < 4; ++r) {
      const float as = asL[r][hh][0] + asL[r][hh][1] + asL[r][hh][2] + asL[r][hh][3];
      e[r] = lrelu(as + ad);
    }
    int cnt = 4;
    if (hasPrev) {
      const float ap = apL[j][hh][0] + apL[j][hh][1] + apL[j][hh][2] + apL[j][hh][3];
      e[4] = lrelu(ap + ad); cnt = 5;
    }
    float mx = e[0];
    for (int k = 1; k < cnt; ++k) mx = fmaxf(mx, e[k]);
    float s = 0.f, ex[5];
    for (int k = 0; k < cnt; ++k) { ex[k] = __expf(e[k] - mx); s += ex[k]; }
    const float inv = 1.f / (s + 1e-16f);
#pragma unroll
    for (int k = 0; k < 5; ++k) alpha[j][tid & 3][k] = (k < cnt) ? ex[k] * inv : 0.f;
  } else if (tid < 20) {
    const int hh = tid - 16;  // audio-even softmax: {self, left eye, right eye}
    const float ad = aeD[hh][0] + aeD[hh][1] + aeD[hh][2] + aeD[hh][3];
    const float es = aeS[hh][0] + aeS[hh][1] + aeS[hh][2] + aeS[hh][3];
    const float s1 = asL[1][hh][0] + asL[1][hh][1] + asL[1][hh][2] + asL[1][hh][3];
    const float s2 = asL[2][hh][0] + asL[2][hh][1] + asL[2][hh][2] + asL[2][hh][3];
    const float e0 = lrelu(es + ad);
    const float e1 = lrelu(s1 + ad);
    const float e2 = lrelu(s2 + ad);
    const float mx = fmaxf(e0, fmaxf(e1, e2));
    const float x0 = __expf(e0 - mx), x1 = __expf(e1 - mx), x2 = __expf(e2 - mx);
    const float inv = 1.f / (x0 + x1 + x2 + 1e-16f);
    alphaA[hh][0] = x0 * inv; alphaA[hh][1] = x1 * inv; alphaA[hh][2] = x2 * inv;
  }
  __syncthreads();

  float4 av[6];
#pragma unroll
  for (int j = 0; j < 4; ++j) {
    const float* al = &alpha[j][head][0];
    float4 acc;
    acc.x = al[0] * hv[0].x + al[1] * hv[1].x + al[2] * hv[2].x + al[3] * hv[3].x;
    acc.y = al[0] * hv[0].y + al[1] * hv[1].y + al[2] * hv[2].y + al[3] * hv[3].y;
    acc.z = al[0] * hv[0].z + al[1] * hv[1].z + al[2] * hv[2].z + al[3] * hv[3].z;
    acc.w = al[0] * hv[0].w + al[1] * hv[1].w + al[2] * hv[2].w + al[3] * hv[3].w;
    if (hasPrev) {
      const float a4 = al[4];
      acc.x += a4 * hp[j].x; acc.y += a4 * hp[j].y;
      acc.z += a4 * hp[j].z; acc.w += a4 * hp[j].w;
    }
    av[j] = acc;
  }
  {
    const float a0 = alphaA[head][0], a1 = alphaA[head][1], a2 = alphaA[head][2];
    float4 acc;
    acc.x = a0 * hae.x + a1 * hv[1].x + a2 * hv[2].x;
    acc.y = a0 * hae.y + a1 * hv[1].y + a2 * hv[2].y;
    acc.z = a0 * hae.z + a1 * hv[1].z + a2 * hv[2].z;
    acc.w = a0 * hae.w + a1 * hv[1].w + a2 * hv[2].w;
    av[4] = acc;
    av[5] = hao;  // odd audio: self-loop only
  }

  size_t rows[6];
#pragma unroll
  for (int j = 0; j < 4; ++j) rows[j] = (size_t)(rb + j);
  rows[4] = (size_t)nodeE; rows[5] = (size_t)nodeO;

  if constexpr (!MEAN) {
    const float4 bv = *(const float4*)(bias + c4);
    u16* ob = (u16*)out;
#pragma unroll
    for (int k = 0; k < 6; ++k) {
      ushort4 o;
      o.x = f2bf(av[k].x + bv.x); o.y = f2bf(av[k].y + bv.y);
      o.z = f2bf(av[k].z + bv.z); o.w = f2bf(av[k].w + bv.w);
      *(ushort4*)(ob + rows[k] * 1024 + c4) = o;
    }
  } else {
    // head-mean + bias, then FUSED LayerNorm (full row resident in block)
#pragma unroll
    for (int k = 0; k < 6; ++k) *(float4*)(&red[k * 1024 + c4]) = av[k];
    __syncthreads();
    const float bb2 = bias[tid];
    float vv[6];
#pragma unroll
    for (int k = 0; k < 6; ++k) {
      const float v = 0.25f * (red[k * 1024 + tid] + red[k * 1024 + tid + 256] +
                               red[k * 1024 + tid + 512] + red[k * 1024 + tid + 768]) + bb2;
      vv[k] = v;
      const float ws = wredx(v);
      const float wq = wredx(v * v);
      if (lane == 0) { stats[k][0][head] = ws; stats[k][1][head] = wq; }
    }
    __syncthreads();
    const float gg = ln_g[tid], lb = ln_b[tid];
    float* of = (float*)out;
#pragma unroll
    for (int k = 0; k < 6; ++k) {
      const float sum = stats[k][0][0] + stats[k][0][1] + stats[k][0][2] + stats[k][0][3];
      const float sq = stats[k][1][0] + stats[k][1][1] + stats[k][1][2] + stats[k][1][3];
      const float mean = sum * (1.f / 256.f);
      const float var = sq * (1.f / 256.f) - mean * mean;
      const float rstd = rsqrtf(var + 1e-5f);
      of[rows[k] * 256 + tid] = (vv[k] - mean) * rstd * gg + lb;
    }
  }
}

// ---------------- pure pooling stage 1 (OLD-row keyed; LN already applied) --
__global__ __launch_bounds__(256) void ln_pool_kernel(
    const float* __restrict__ xf, float* __restrict__ part) {
  __shared__ float sh[1024];
  const int tid = threadIdx.x;
  const int wave = tid >> 6, lane = tid & 63;
  const int node0 = blockIdx.x * 64 + wave * 16;  // OLD row base (one region)
  const bool isAud = node0 >= 32768;
  const int reg = isAud ? 4 : (node0 >> 13);
  const int bt0 = node0 & 8191;
  float4 acc = {0.f, 0.f, 0.f, 0.f};
  for (int i = 0; i < 16; ++i) {
    const size_t nrow = isAud ? (size_t)(node0 + i) : (size_t)((bt0 + i) * 4 + reg);
    const float4 v = *(const float4*)(xf + nrow * 256 + lane * 4);
    acc.x += v.x; acc.y += v.y; acc.z += v.z; acc.w += v.w;
  }
  *(float4*)(&sh[wave * 256 + lane * 4]) = acc;
  __syncthreads();
  const float s = sh[tid] + sh[256 + tid] + sh[512 + tid] + sh[768 + tid];
  part[(size_t)blockIdx.x * 256 + tid] = s;
}

__global__ __launch_bounds__(256) void pool2_kernel(const float* __restrict__ part,
                                                    float* __restrict__ out) {
  const int chunk = blockIdx.x;
  const int c = threadIdx.x;
  float s = 0.f;
  for (int i = 0; i < 48; ++i) s += part[(size_t)(chunk * 48 + i) * 256 + c];
  out[chunk * 256 + c] = s * (1.f / 3072.f);
}

// ---------------------------------------------------------------------------
extern "C" void kernel_launch(void* const* d_in, const int* in_sizes, int n_in,
                              void* d_out, int out_size, void* d_ws, size_t ws_size,
                              hipStream_t stream) {
  const float* x_reg[4] = {(const float*)d_in[0], (const float*)d_in[1],
                           (const float*)d_in[2], (const float*)d_in[3]};
  const float* audio = (const float*)d_in[4];
  const float* w_reg[4] = {(const float*)d_in[5], (const float*)d_in[7],
                           (const float*)d_in[9], (const float*)d_in[11]};
  const float* b_reg[4] = {(const float*)d_in[6], (const float*)d_in[8],
                           (const float*)d_in[10], (const float*)d_in[12]};
  const float* w_aud = (const float*)d_in[13];
  const float* b_aud = (const float*)d_in[14];
  const float* Wl[3] = {(const float*)d_in[15], (const float*)d_in[19],
                        (const float*)d_in[23]};
  const float* as_in[3] = {(const float*)d_in[16], (const float*)d_in[20],
                           (const float*)d_in[24]};
  const float* ad_in[3] = {(const float*)d_in[17], (const float*)d_in[21],
                           (const float*)d_in[25]};
  const float* bias_l[3] = {(const float*)d_in[18], (const float*)d_in[22],
                            (const float*)d_in[26]};
  const float* ln_g = (const float*)d_in[27];
  const float* ln_b = (const float*)d_in[28];

  // workspace layout (<200 MiB)
  char* ws = (char*)d_ws;
  u16* h_bf = (u16*)ws;                    // [N,1024] bf16 (96 MiB)
  float* part = (float*)ws;                // ln partials (h dead by then)
  u16* xb = (u16*)(ws + 100663296);        // [N,1024] bf16 x buffer
  float* xf = (float*)xb;                  // layer-2 output [N,256] fp32
  u16* wt = (u16*)(ws + 201326592);        // packed bf16 weights (~5.8 MiB)

  u16* wtp[5];
  for (int r = 0; r < 5; ++r) wtp[r] = wt + (size_t)r * 131072;
  u16* wt0 = wt + 655360;   // 512 frags
  u16* wt1 = wt + 917504;   // 2048 frags
  u16* wt2 = wt + 1966080;  // 2048 frags

  // 1) pack all weights into MFMA fragment order
  PK pk;
  for (int r = 0; r < 4; ++r) { pk.W[r] = w_reg[r]; pk.P[r] = wtp[r]; pk.KB[r] = 16; pk.NN[r] = 256; }
  pk.W[4] = w_aud; pk.P[4] = wtp[4]; pk.KB[4] = 16; pk.NN[4] = 256;
  pk.W[5] = Wl[0]; pk.P[5] = wt0; pk.KB[5] = 8;  pk.NN[5] = 1024;
  pk.W[6] = Wl[1]; pk.P[6] = wt1; pk.KB[6] = 32; pk.NN[6] = 1024;
  pk.W[7] = Wl[2]; pk.P[7] = wt2; pk.KB[7] = 32; pk.NN[7] = 1024;
  pk.st[0] = 0;
  {
    const int nfr[8] = {256, 256, 256, 256, 256, 512, 2048, 2048};
    int acc = 0;
    for (int e = 0; e < 8; ++e) { acc += nfr[e]; pk.st[e + 1] = acc; }
  }
  pack_kernel<<<pk.st[8] / 4, 256, 0, stream>>>(pk);

  // 2) fused input projections (fp32 in, bf16 out) -> x0 [N,256] interleaved
  ProjArgs pa;
  for (int r = 0; r < 4; ++r) { pa.x[r] = x_reg[r]; pa.w[r] = wtp[r]; pa.b[r] = b_reg[r]; }
  pa.x[4] = audio; pa.w[4] = wtp[4]; pa.b[4] = b_aud;
  proj_kernel<<<dim3(2, 384), 256, 0, stream>>>(pa, xb);

  // 3) three GAT layers: R13 gemm -> agg (wred4)
  const size_t dynLds = 6 * 1024 * sizeof(float);
  gemm_kernel<<<dim3(8, 384), 256, 0, stream>>>(xb, wt0, h_bf, 256, 1024);
  agg_kernel<false><<<8192, 256, 0, stream>>>(h_bf, as_in[0], ad_in[0],
                                              bias_l[0], ln_g, ln_b, xb);
  gemm_kernel<<<dim3(8, 384), 256, 0, stream>>>(xb, wt1, h_bf, 1024, 1024);
  agg_kernel<false><<<8192, 256, 0, stream>>>(h_bf, as_in[1], ad_in[1],
                                              bias_l[1], ln_g, ln_b, xb);
  gemm_kernel<<<dim3(8, 384), 256, 0, stream>>>(xb, wt2, h_bf, 1024, 1024);
  agg_kernel<true><<<8192, 256, dynLds, stream>>>(h_bf, as_in[2], ad_in[2],
                                                  bias_l[2], ln_g, ln_b, xf);

  // 4) pooling -> out [16,256]  (LN already applied in agg L2)
  ln_pool_kernel<<<768, 256, 0, stream>>>(xf, part);
  pool2_kernel<<<16, 256, 0, stream>>>(part, (float*)d_out);
}

// Round 10
// 588.947 us; speedup vs baseline: 1.1231x; 1.0250x over previous
//
#include <hip/hip_runtime.h>

// ---------------------------------------------------------------------------
// MultiModalRelationGraph — R23  (= R20 exact revert + single-A-read proj)
// - R22 post-mortem: wred4+LN-fusion = -5.6µs vs R20 (null/negative; agg is
//   latency/issue-bound: R21 diag = not read-BW (L2-warm pass same speed),
//   R19 = not MLP-starved, R22 = not shuffle-count). Agg CLOSED at risk
//   budget; gemm CLOSED (R14-R18). Reverted to R20-exact config (598.1 best).
// - R23 change: proj was reading+converting the SAME fp32 A rows twice
//   (dim3(2,384) column blocks): 201MB instead of 100.5MB. Now 384 blocks x
//   512 thr (8 waves = 2 row x 4 col covering 128x256), A staged once/k0.
//   Staging: thread stages one (row=tid>>2, chunk=tid&3); row-keyed swizzle
//   formula unchanged. Per-wave acc[4][4], B-ptrs, frag reads, epilogue
//   verbatim. Saves ~100MB fp32 read + half the f2bf VALU.
// - Pre-commit: total >= 598 -> ROOFLINE next round at best config.
// - Ledger: wred4 null, LN-fusion ~neutral (R22); agg not read-BW-bound
//   (R21 diag); odd-audio bypass racy (R21); paired agg kills TLP (R19);
//   occupancy forcing null (R18); 32x32 bank-conflicts (R17); BK=32 ring
//   B-latency (R16); 256² lockstep null (R15); strip-mining kills agg TLP
//   (R8/R9); atomics flood (R10); pure-global A+B L2-bound (R5); big AGPR
//   kills occ (R3); proj×W0 fusion re-does cvt (R12).
// Layout: region node (reg,b,t) -> row 4*(b*512+t)+reg; audio 32768+b*1024+ta.
// ---------------------------------------------------------------------------

typedef unsigned short u16;
typedef unsigned int u32;
typedef __bf16 bf16x8 __attribute__((ext_vector_type(8)));
typedef float f32x4 __attribute__((ext_vector_type(4)));

#define ASYNC16(gp, lp)                                                        \
  __builtin_amdgcn_global_load_lds(                                            \
      (const __attribute__((address_space(1))) void*)(gp),                     \
      (__attribute__((address_space(3))) void*)(lp), 16, 0, 0)

__device__ __forceinline__ u16 f2bf(float f) {
  union { float f; u32 u; } v; v.f = f;
  u32 u = v.u + 0x7FFFu + ((v.u >> 16) & 1u);  // RNE
  return (u16)(u >> 16);
}
__device__ __forceinline__ float bf2f(u16 x) {
  union { u32 u; float f; } v; v.u = ((u32)x) << 16;
  return v.f;
}
__device__ __forceinline__ float4 cvt4(ushort4 s) {
  float4 r; r.x = bf2f(s.x); r.y = bf2f(s.y); r.z = bf2f(s.z); r.w = bf2f(s.w);
  return r;
}
__device__ __forceinline__ float lrelu(float v) { return v > 0.f ? v : 0.2f * v; }
__device__ __forceinline__ float dot4(float4 a, float4 b) {
  return a.x * b.x + a.y * b.y + a.z * b.z + a.w * b.w;
}
__device__ __forceinline__ float wred(float v) {  // lane 0 valid
#pragma unroll
  for (int off = 32; off; off >>= 1) v += __shfl_down(v, off);
  return v;
}
__device__ __forceinline__ float wredx(float v) {  // all lanes valid
#pragma unroll
  for (int off = 32; off; off >>= 1) v += __shfl_xor(v, off);
  return v;
}

// ---------------- weight pack: W [K][N] fp32 -> MFMA B-fragment order -------
struct PK { const float* W[8]; u16* P[8]; int KB[8]; int NN[8]; int st[9]; };
__global__ __launch_bounds__(256) void pack_kernel(PK p) {
  const int f = blockIdx.x * 4 + (threadIdx.x >> 6);
  const int lane = threadIdx.x & 63;
  int e = 0;
  while (f >= p.st[e + 1]) ++e;
  const int local = f - p.st[e];
  const int KB = p.KB[e], N = p.NN[e];
  const int nt = local / KB, kb = local % KB;
  const float* W = p.W[e] + (size_t)(kb * 32 + (lane >> 4) * 8) * N + nt * 16 + (lane & 15);
  u16* dst = p.P[e] + ((size_t)local * 64 + lane) * 8;
  u16 o[8];
#pragma unroll
  for (int j = 0; j < 8; ++j) o[j] = f2bf(W[(size_t)j * N]);
  *(uint4*)dst = *(uint4*)o;
}

// ---------------- layer GEMM: C[M,N]=A[M,K]@W^T; BK=64 dbuf, B hoisted ------
// R13 verbatim (proven, 68 VGPR, 0 bank conflicts). Row-order agnostic.
__global__ __launch_bounds__(256) void gemm_kernel(
    const u16* __restrict__ A, const u16* __restrict__ Bp, u16* __restrict__ C,
    int K, int ldc) {
  __shared__ __align__(16) u16 As[2][2][128 * 32];
  const int KB = K >> 5;
  const int KB2 = K >> 6;
  const int w = blockIdx.y * 8 + blockIdx.x;
  const int xcd = w & 7, m = w >> 3;
  const int blockCol = (m & 7) * 128;
  const int blockRow = ((m >> 3) * 8 + xcd) * 128;
  const int tid = threadIdx.x;
  const int wave = tid >> 6, lane = tid & 63;
  const int wr = (wave >> 1) * 64, wc = (wave & 1) * 64;
  const int lr = lane & 15, lq = lane >> 4;
  const int sRow = wave * 16 + (lane >> 2);
  const int sGc = (lane & 3) ^ ((sRow >> 1) & 3);
  const size_t aOff0 = (size_t)(blockRow + sRow) * K + sGc * 8;
  const size_t aOff1 = aOff0 + (size_t)64 * K;
  const int ldsOff0 = wave * 512;
  const int ldsOff1 = 2048 + wave * 512;

  const u16* Bn[4];
#pragma unroll
  for (int ni = 0; ni < 4; ++ni)
    Bn[ni] = Bp + ((size_t)(((blockCol + wc) >> 4) + ni) * KB) * 512 + lane * 8;

  f32x4 acc[4][4] = {};

#pragma unroll
  for (int h = 0; h < 2; ++h) {
    ASYNC16(A + aOff0 + h * 32, As[0][h] + ldsOff0);
    ASYNC16(A + aOff1 + h * 32, As[0][h] + ldsOff1);
  }
  __syncthreads();

  for (int kb2 = 0; kb2 < KB2; ++kb2) {
    const int cb = kb2 & 1;
    bf16x8 bfr[2][4];
#pragma unroll
    for (int h = 0; h < 2; ++h)
#pragma unroll
      for (int ni = 0; ni < 4; ++ni)
        bfr[h][ni] = *(const bf16x8*)(Bn[ni] + (size_t)(kb2 * 2 + h) * 512);
    if (kb2 + 1 < KB2) {
      const size_t k1 = (size_t)(kb2 + 1) * 64;
#pragma unroll
      for (int h = 0; h < 2; ++h) {
        ASYNC16(A + aOff0 + k1 + h * 32, As[cb ^ 1][h] + ldsOff0);
        ASYNC16(A + aOff1 + k1 + h * 32, As[cb ^ 1][h] + ldsOff1);
      }
    }
#pragma unroll
    for (int h = 0; h < 2; ++h) {
      const u16* cur = As[cb][h];
      bf16x8 af[4];
#pragma unroll
      for (int mi = 0; mi < 4; ++mi) {
        const int R = wr + mi * 16 + lr;
        const int cp = lq ^ ((R >> 1) & 3);
        af[mi] = *(const bf16x8*)(cur + R * 32 + cp * 8);
      }
#pragma unroll
      for (int mi = 0; mi < 4; ++mi)
#pragma unroll
        for (int ni = 0; ni < 4; ++ni)
          acc[mi][ni] = __builtin_amdgcn_mfma_f32_16x16x32_bf16(af[mi], bfr[h][ni],
                                                                acc[mi][ni], 0, 0, 0);
    }
    __syncthreads();
  }
#pragma unroll
  for (int mi = 0; mi < 4; ++mi)
#pragma unroll
    for (int ni = 0; ni < 4; ++ni) {
      const int col = blockCol + wc + ni * 16 + lr;
#pragma unroll
      for (int r = 0; r < 4; ++r) {
        const int row = blockRow + wr + mi * 16 + lq * 4 + r;
        C[(size_t)row * ldc + col] = f2bf(acc[mi][ni][r]);
      }
    }
}

// ---------------- fused input projection (fp32 A in-register cvt) -----------
// 384 blocks x 512 thr (8 waves: 2 row x 4 col -> 128x256). A staged ONCE per
// k0 (single fp32 read of each row). Output rows remapped: region -> 4*bt+reg.
struct ProjArgs { const float* x[5]; const u16* w[5]; const float* b[5]; };
__global__ __launch_bounds__(512) void proj_kernel(ProjArgs pa,
                                                   u16* __restrict__ C) {
  __shared__ __align__(16) u16 As[128 * 32];
  const int blockRow = blockIdx.x * 128;
  const int reg = blockRow >= 32768 ? 4 : (blockRow >> 13);
  const int regBase = reg == 4 ? 32768 : reg * 8192;
  const float* Af = pa.x[reg] + (size_t)(blockRow - regBase) * 512;
  const u16* Bp = pa.w[reg];
  const int tid = threadIdx.x;
  const int wave = tid >> 6, lane = tid & 63;
  const int wr = (wave >> 2) * 64, wc = (wave & 3) * 64;
  const int lr = lane & 15, lq = lane >> 4;
  const int rr = tid >> 2;           // 512 threads -> rows 0..127, once each
  const int cphys = tid & 3;
  const int sGc = cphys ^ ((tid >> 3) & 3);  // row-keyed swizzle (row = tid>>2)

  const u16* Bn[4];
#pragma unroll
  for (int ni = 0; ni < 4; ++ni)
    Bn[ni] = Bp + ((size_t)((wc >> 4) + ni) * 16) * 512 + lane * 8;

  f32x4 acc[4][4] = {};

  for (int k0 = 0; k0 < 512; k0 += 32) {
    __syncthreads();
    bf16x8 bfr[4];
#pragma unroll
    for (int ni = 0; ni < 4; ++ni)
      bfr[ni] = *(const bf16x8*)(Bn[ni] + (size_t)k0 * 16);
    {
      const float* ap = Af + (size_t)rr * 512 + k0 + sGc * 8;
      float4 f0 = *(const float4*)(ap);
      float4 f1 = *(const float4*)(ap + 4);
      uint4 pk;
      pk.x = (u32)f2bf(f0.x) | ((u32)f2bf(f0.y) << 16);
      pk.y = (u32)f2bf(f0.z) | ((u32)f2bf(f0.w) << 16);
      pk.z = (u32)f2bf(f1.x) | ((u32)f2bf(f1.y) << 16);
      pk.w = (u32)f2bf(f1.z) | ((u32)f2bf(f1.w) << 16);
      *(uint4*)(&As[rr * 32 + cphys * 8]) = pk;
    }
    __syncthreads();
    bf16x8 af[4];
#pragma unroll
    for (int mi = 0; mi < 4; ++mi) {
      const int R = wr + mi * 16 + lr;
      const int cp = lq ^ ((R >> 1) & 3);
      af[mi] = *(const bf16x8*)(&As[R * 32 + cp * 8]);
    }
#pragma unroll
    for (int mi = 0; mi < 4; ++mi)
#pragma unroll
      for (int ni = 0; ni < 4; ++ni)
        acc[mi][ni] = __builtin_amdgcn_mfma_f32_16x16x32_bf16(af[mi], bfr[ni],
                                                              acc[mi][ni], 0, 0, 0);
  }
  const float* bias = pa.b[reg];
#pragma unroll
  for (int mi = 0; mi < 4; ++mi)
#pragma unroll
    for (int ni = 0; ni < 4; ++ni) {
      const int col = wc + ni * 16 + lr;
      const float bv = bias[col];
#pragma unroll
      for (int r = 0; r < 4; ++r) {
        const int row = blockRow + wr + mi * 16 + lq * 4 + r;
        const int nrow = (reg == 4) ? row : ((row - regBase) * 4 + reg);
        C[(size_t)nrow * 256 + col] = f2bf(acc[mi][ni][r] + bv);
      }
    }
}

// ---------------- merged aggregation: block (b,t) -> 6 dst nodes ------------
// R20 verbatim. Interleaved layout: hv = [4bt..4bt+3] contiguous; hp =
// preceding 8KB (same-XCD L2-hot via chunking swizzle); audio unchanged.
template <bool MEAN>
__global__ __launch_bounds__(256) void agg_kernel(
    const u16* __restrict__ h, const float* __restrict__ a_s,
    const float* __restrict__ a_d, const float* __restrict__ bias,
    void* __restrict__ out) {
  extern __shared__ float red[];  // MEAN only: [6][1024]
  const int tid = threadIdx.x;
  const int head = tid >> 6, lane = tid & 63;
  const int c4 = tid * 4;
  const float4 sa = *(const float4*)(a_s + c4);
  const float4 da = *(const float4*)(a_d + c4);
  __shared__ float asL[4][4], adL[4][4], apL[4][4], aeS[4], aeD[4];
  __shared__ float alpha[4][4][5], alphaA[4][3];

  const int bid = blockIdx.x;
  const int bt = ((bid & 7) << 10) | (bid >> 3);  // bijective XCD chunking
  const int b = bt >> 9, t = bt & 511;
  const bool hasPrev = t > 0;
  const int btp = hasPrev ? bt - 1 : bt;  // clamped: loads valid, result unused at t==0
  const int rb = bt * 4, rbp = btp * 4;   // interleaved region row bases
  const int nodeE = 32768 + b * 1024 + 2 * t;
  const int nodeO = nodeE + 1;

  // ---- batched raw loads (no cvt until all issued) ----
  ushort4 rv[4], rp[4], raeR, raoR;
#pragma unroll
  for (int r = 0; r < 4; ++r)
    rv[r] = *(const ushort4*)(h + (size_t)(rb + r) * 1024 + c4);
  raeR = *(const ushort4*)(h + (size_t)nodeE * 1024 + c4);
  raoR = *(const ushort4*)(h + (size_t)nodeO * 1024 + c4);
#pragma unroll
  for (int r = 0; r < 4; ++r)
    rp[r] = *(const ushort4*)(h + (size_t)(rbp + r) * 1024 + c4);

  float4 hv[4], hp[4];
#pragma unroll
  for (int r = 0; r < 4; ++r) hv[r] = cvt4(rv[r]);
  float4 hae = cvt4(raeR), hao = cvt4(raoR);
#pragma unroll
  for (int r = 0; r < 4; ++r) hp[r] = cvt4(rp[r]);

  // dots (wave w == head w); lane0-valid wred, stash to LDS
#pragma unroll
  for (int r = 0; r < 4; ++r) {
    float ss = wred(dot4(hv[r], sa));
    float dd = wred(dot4(hv[r], da));
    float sp = hasPrev ? wred(dot4(hp[r], sa)) : 0.f;
    if (lane == 0) { asL[r][head] = ss; adL[r][head] = dd; apL[r][head] = sp; }
  }
  {
    float se = wred(dot4(hae, sa));
    float de = wred(dot4(hae, da));
    if (lane == 0) { aeS[head] = se; aeD[head] = de; }
  }
  __syncthreads();
  if (tid < 16) {
    const int j = tid >> 2, hh = tid & 3;
    const float ad = adL[j][hh];
    float e[5];
#pragma unroll
    for (int r = 0; r < 4; ++r) e[r] = lrelu(asL[r][hh] + ad);
    int cnt = 4;
    if (hasPrev) { e[4] = lrelu(apL[j][hh] + ad); cnt = 5; }
    float mx = e[0];
    for (int k = 1; k < cnt; ++k) mx = fmaxf(mx, e[k]);
    float s = 0.f, ex[5];
    for (int k = 0; k < cnt; ++k) { ex[k] = __expf(e[k] - mx); s += ex[k]; }
    const float inv = 1.f / (s + 1e-16f);
#pragma unroll
    for (int k = 0; k < 5; ++k) alpha[j][hh][k] = (k < cnt) ? ex[k] * inv : 0.f;
  } else if (tid < 20) {
    const int hh = tid - 16;  // audio-even softmax: {self, left eye, right eye}
    const float ad = aeD[hh];
    const float e0 = lrelu(aeS[hh] + ad);
    const float e1 = lrelu(asL[1][hh] + ad);
    const float e2 = lrelu(asL[2][hh] + ad);
    const float mx = fmaxf(e0, fmaxf(e1, e2));
    const float x0 = __expf(e0 - mx), x1 = __expf(e1 - mx), x2 = __expf(e2 - mx);
    const float inv = 1.f / (x0 + x1 + x2 + 1e-16f);
    alphaA[hh][0] = x0 * inv; alphaA[hh][1] = x1 * inv; alphaA[hh][2] = x2 * inv;
  }
  __syncthreads();

  float4 av[6];
#pragma unroll
  for (int j = 0; j < 4; ++j) {
    const float* al = &alpha[j][head][0];
    float4 acc;
    acc.x = al[0] * hv[0].x + al[1] * hv[1].x + al[2] * hv[2].x + al[3] * hv[3].x;
    acc.y = al[0] * hv[0].y + al[1] * hv[1].y + al[2] * hv[2].y + al[3] * hv[3].y;
    acc.z = al[0] * hv[0].z + al[1] * hv[1].z + al[2] * hv[2].z + al[3] * hv[3].z;
    acc.w = al[0] * hv[0].w + al[1] * hv[1].w + al[2] * hv[2].w + al[3] * hv[3].w;
    if (hasPrev) {
      const float a4 = al[4];
      acc.x += a4 * hp[j].x; acc.y += a4 * hp[j].y;
      acc.z += a4 * hp[j].z; acc.w += a4 * hp[j].w;
    }
    av[j] = acc;
  }
  {
    const float a0 = alphaA[head][0], a1 = alphaA[head][1], a2 = alphaA[head][2];
    float4 acc;
    acc.x = a0 * hae.x + a1 * hv[1].x + a2 * hv[2].x;
    acc.y = a0 * hae.y + a1 * hv[1].y + a2 * hv[2].y;
    acc.z = a0 * hae.z + a1 * hv[1].z + a2 * hv[2].z;
    acc.w = a0 * hae.w + a1 * hv[1].w + a2 * hv[2].w;
    av[4] = acc;
    av[5] = hao;  // odd audio: self-loop only
  }

  size_t rows[6];
#pragma unroll
  for (int j = 0; j < 4; ++j) rows[j] = (size_t)(rb + j);
  rows[4] = (size_t)nodeE; rows[5] = (size_t)nodeO;

  if constexpr (!MEAN) {
    const float4 bv = *(const float4*)(bias + c4);
    u16* ob = (u16*)out;
#pragma unroll
    for (int k = 0; k < 6; ++k) {
      ushort4 o;
      o.x = f2bf(av[k].x + bv.x); o.y = f2bf(av[k].y + bv.y);
      o.z = f2bf(av[k].z + bv.z); o.w = f2bf(av[k].w + bv.w);
      *(ushort4*)(ob + rows[k] * 1024 + c4) = o;
    }
  } else {
#pragma unroll
    for (int k = 0; k < 6; ++k) *(float4*)(&red[k * 1024 + c4]) = av[k];
    __syncthreads();
    const float bb = bias[tid];
    float* of = (float*)out;
#pragma unroll
    for (int k = 0; k < 6; ++k) {
      const float v = 0.25f * (red[k * 1024 + tid] + red[k * 1024 + tid + 256] +
                               red[k * 1024 + tid + 512] + red[k * 1024 + tid + 768]) + bb;
      of[rows[k] * 256 + tid] = v;
    }
  }
}

// ---------------- LayerNorm(256) + block pooling (OLD-row keyed) ------------
// R20 verbatim: block p handles OLD rows [64p,64p+64); region rows gather
// stride-4 from interleaved xf.
__global__ __launch_bounds__(256) void ln_pool_kernel(
    const float* __restrict__ xf, const float* __restrict__ g,
    const float* __restrict__ bb, float* __restrict__ part) {
  __shared__ float sh[1024];
  const int tid = threadIdx.x;
  const int wave = tid >> 6, lane = tid & 63;
  const int node0 = blockIdx.x * 64 + wave * 16;  // OLD row base (one region)
  const bool isAud = node0 >= 32768;
  const int reg = isAud ? 4 : (node0 >> 13);
  const int bt0 = node0 & 8191;
  const float4 g4 = *(const float4*)(g + lane * 4);
  const float4 b4 = *(const float4*)(bb + lane * 4);
  float4 acc = {0.f, 0.f, 0.f, 0.f};
  for (int i = 0; i < 16; ++i) {
    const size_t nrow = isAud ? (size_t)(node0 + i) : (size_t)((bt0 + i) * 4 + reg);
    const float4 v = *(const float4*)(xf + nrow * 256 + lane * 4);
    const float s = wredx(v.x + v.y + v.z + v.w);
    const float q = wredx(v.x * v.x + v.y * v.y + v.z * v.z + v.w * v.w);
    const float mean = s * (1.f / 256.f);
    const float var = q * (1.f / 256.f) - mean * mean;
    const float rstd = rsqrtf(var + 1e-5f);
    acc.x += (v.x - mean) * rstd * g4.x + b4.x;
    acc.y += (v.y - mean) * rstd * g4.y + b4.y;
    acc.z += (v.z - mean) * rstd * g4.z + b4.z;
    acc.w += (v.w - mean) * rstd * g4.w + b4.w;
  }
  *(float4*)(&sh[wave * 256 + lane * 4]) = acc;
  __syncthreads();
  const float s = sh[tid] + sh[256 + tid] + sh[512 + tid] + sh[768 + tid];
  part[(size_t)blockIdx.x * 256 + tid] = s;
}

__global__ __launch_bounds__(256) void pool2_kernel(const float* __restrict__ part,
                                                    float* __restrict__ out) {
  const int chunk = blockIdx.x;
  const int c = threadIdx.x;
  float s = 0.f;
  for (int i = 0; i < 48; ++i) s += part[(size_t)(chunk * 48 + i) * 256 + c];
  out[chunk * 256 + c] = s * (1.f / 3072.f);
}

// ---------------------------------------------------------------------------
extern "C" void kernel_launch(void* const* d_in, const int* in_sizes, int n_in,
                              void* d_out, int out_size, void* d_ws, size_t ws_size,
                              hipStream_t stream) {
  const float* x_reg[4] = {(const float*)d_in[0], (const float*)d_in[1],
                           (const float*)d_in[2], (const float*)d_in[3]};
  const float* audio = (const float*)d_in[4];
  const float* w_reg[4] = {(const float*)d_in[5], (const float*)d_in[7],
                           (const float*)d_in[9], (const float*)d_in[11]};
  const float* b_reg[4] = {(const float*)d_in[6], (const float*)d_in[8],
                           (const float*)d_in[10], (const float*)d_in[12]};
  const float* w_aud = (const float*)d_in[13];
  const float* b_aud = (const float*)d_in[14];
  const float* Wl[3] = {(const float*)d_in[15], (const float*)d_in[19],
                        (const float*)d_in[23]};
  const float* as_in[3] = {(const float*)d_in[16], (const float*)d_in[20],
                           (const float*)d_in[24]};
  const float* ad_in[3] = {(const float*)d_in[17], (const float*)d_in[21],
                           (const float*)d_in[25]};
  const float* bias_l[3] = {(const float*)d_in[18], (const float*)d_in[22],
                            (const float*)d_in[26]};
  const float* ln_g = (const float*)d_in[27];
  const float* ln_b = (const float*)d_in[28];

  // workspace layout (<200 MiB)
  char* ws = (char*)d_ws;
  u16* h_bf = (u16*)ws;                    // [N,1024] bf16 (96 MiB)
  float* part = (float*)ws;                // ln partials (h dead by then)
  u16* xb = (u16*)(ws + 100663296);        // [N,1024] bf16 x buffer
  float* xf = (float*)xb;                  // layer-2 output [N,256] fp32
  u16* wt = (u16*)(ws + 201326592);        // packed bf16 weights (~5.8 MiB)

  u16* wtp[5];
  for (int r = 0; r < 5; ++r) wtp[r] = wt + (size_t)r * 131072;
  u16* wt0 = wt + 655360;   // 512 frags
  u16* wt1 = wt + 917504;   // 2048 frags
  u16* wt2 = wt + 1966080;  // 2048 frags

  // 1) pack all weights into MFMA fragment order
  PK pk;
  for (int r = 0; r < 4; ++r) { pk.W[r] = w_reg[r]; pk.P[r] = wtp[r]; pk.KB[r] = 16; pk.NN[r] = 256; }
  pk.W[4] = w_aud; pk.P[4] = wtp[4]; pk.KB[4] = 16; pk.NN[4] = 256;
  pk.W[5] = Wl[0]; pk.P[5] = wt0; pk.KB[5] = 8;  pk.NN[5] = 1024;
  pk.W[6] = Wl[1]; pk.P[6] = wt1; pk.KB[6] = 32; pk.NN[6] = 1024;
  pk.W[7] = Wl[2]; pk.P[7] = wt2; pk.KB[7] = 32; pk.NN[7] = 1024;
  pk.st[0] = 0;
  {
    const int nfr[8] = {256, 256, 256, 256, 256, 512, 2048, 2048};
    int acc = 0;
    for (int e = 0; e < 8; ++e) { acc += nfr[e]; pk.st[e + 1] = acc; }
  }
  pack_kernel<<<pk.st[8] / 4, 256, 0, stream>>>(pk);

  // 2) fused input projections (fp32 in, bf16 out) -> x0 [N,256] interleaved
  //    Single-A-read: 384 blocks x 512 threads (8 waves cover 128x256).
  ProjArgs pa;
  for (int r = 0; r < 4; ++r) { pa.x[r] = x_reg[r]; pa.w[r] = wtp[r]; pa.b[r] = b_reg[r]; }
  pa.x[4] = audio; pa.w[4] = wtp[4]; pa.b[4] = b_aud;
  proj_kernel<<<384, 512, 0, stream>>>(pa, xb);

  // 3) three GAT layers: R13 gemm -> interleaved agg (R20 verbatim)
  const u16* wl[3] = {wt0, wt1, wt2};
  const int Kl[3] = {256, 1024, 1024};
  const size_t dynLds = 6 * 1024 * sizeof(float);
  for (int l = 0; l < 3; ++l) {
    gemm_kernel<<<dim3(8, 384), 256, 0, stream>>>(xb, wl[l], h_bf, Kl[l], 1024);
    if (l < 2)
      agg_kernel<false><<<8192, 256, 0, stream>>>(h_bf, as_in[l], ad_in[l],
                                                  bias_l[l], xb);
    else
      agg_kernel<true><<<8192, 256, dynLds, stream>>>(h_bf, as_in[l], ad_in[l],
                                                      bias_l[l], xf);
  }

  // 4) LayerNorm + chunk pooling -> out [16,256]
  ln_pool_kernel<<<768, 256, 0, stream>>>(xf, ln_g, ln_b, part);
  pool2_kernel<<<16, 256, 0, stream>>>(part, (float*)d_out);
}